// Round 3
// baseline (166.842 us; speedup 1.0000x reference)
//
#include <hip/hip_runtime.h>

// Occlusion: out = (1/NUM_GRAPHS) * sum_e exp(-||pos[dst_e] - pos[src_e]||)
// batch_idx is irrelevant (all segment ids in range; mean over segments ==
// total_sum / NUM_GRAPHS).
//
// Structure: kernel1 computes per-block partial sums into d_ws (no atomics,
// no memset needed); kernel2 (1 block) reduces 2048 partials -> d_out.
// Latency-bound gather kernel: fully unrolled (exactly 4 groups/thread),
// all 32 gathers hoisted for max memory-level parallelism; index stream
// loaded nontemporally to keep the 1MB pos table L2-resident.

#define N_EDGES_C   8388608
#define GRID1       2048
#define BLOCK1      256
#define TOTAL_THR   (GRID1 * BLOCK1)          // 524288
#define N_GROUPS    (N_EDGES_C / 4)           // 2097152 int4 groups
#define GROUPS_PER_THREAD (N_GROUPS / TOTAL_THR)  // exactly 4
#define INV_NUM_GRAPHS (1.0f / 1024.0f)

typedef int v4i __attribute__((ext_vector_type(4)));  // native vector: nt-load OK

__global__ __launch_bounds__(BLOCK1) void occlusion_partial(
    const float2* __restrict__ pos,    // [N_NODES]
    const v4i*    __restrict__ src4,   // [E/4]
    const v4i*    __restrict__ dst4,   // [E/4]
    float*        __restrict__ partials) // [GRID1]
{
    const int tid = blockIdx.x * blockDim.x + threadIdx.x;

    // --- hoist all index loads (streaming; nontemporal to spare L2) ---
    v4i s[GROUPS_PER_THREAD], d[GROUPS_PER_THREAD];
    #pragma unroll
    for (int j = 0; j < GROUPS_PER_THREAD; ++j) {
        s[j] = __builtin_nontemporal_load(&src4[tid + j * TOTAL_THR]);
        d[j] = __builtin_nontemporal_load(&dst4[tid + j * TOTAL_THR]);
    }

    // --- hoist all 32 gathers (16 edges x 2 endpoints) ---
    float2 ps[16], pd[16];
    #pragma unroll
    for (int j = 0; j < GROUPS_PER_THREAD; ++j) {
        #pragma unroll
        for (int k = 0; k < 4; ++k) {
            ps[j * 4 + k] = pos[s[j][k]];
            pd[j * 4 + k] = pos[d[j][k]];
        }
    }

    // --- arithmetic (4 independent accumulator chains) ---
    float acc0 = 0.f, acc1 = 0.f, acc2 = 0.f, acc3 = 0.f;
    #pragma unroll
    for (int k = 0; k < 4; ++k) {
        float dx, dy;
        dx = pd[k +  0].x - ps[k +  0].x;  dy = pd[k +  0].y - ps[k +  0].y;
        acc0 += __expf(-sqrtf(dx * dx + dy * dy));
        dx = pd[k +  4].x - ps[k +  4].x;  dy = pd[k +  4].y - ps[k +  4].y;
        acc1 += __expf(-sqrtf(dx * dx + dy * dy));
        dx = pd[k +  8].x - ps[k +  8].x;  dy = pd[k +  8].y - ps[k +  8].y;
        acc2 += __expf(-sqrtf(dx * dx + dy * dy));
        dx = pd[k + 12].x - ps[k + 12].x;  dy = pd[k + 12].y - ps[k + 12].y;
        acc3 += __expf(-sqrtf(dx * dx + dy * dy));
    }
    float acc = (acc0 + acc1) + (acc2 + acc3);

    // --- wave-64 butterfly reduce ---
    #pragma unroll
    for (int off = 32; off > 0; off >>= 1)
        acc += __shfl_down(acc, off, 64);

    __shared__ float wave_sums[BLOCK1 / 64];
    const int lane = threadIdx.x & 63;
    const int wid  = threadIdx.x >> 6;
    if (lane == 0) wave_sums[wid] = acc;
    __syncthreads();

    if (threadIdx.x == 0) {
        partials[blockIdx.x] = (wave_sums[0] + wave_sums[1]) +
                               (wave_sums[2] + wave_sums[3]);
    }
}

__global__ __launch_bounds__(256) void occlusion_final(
    const float* __restrict__ partials,  // [GRID1]
    float*       __restrict__ out)       // [1]
{
    float a = 0.f;
    #pragma unroll
    for (int i = 0; i < GRID1 / 256; ++i)
        a += partials[threadIdx.x + i * 256];

    #pragma unroll
    for (int off = 32; off > 0; off >>= 1)
        a += __shfl_down(a, off, 64);

    __shared__ float w[4];
    if ((threadIdx.x & 63) == 0) w[threadIdx.x >> 6] = a;
    __syncthreads();
    if (threadIdx.x == 0)
        out[0] = ((w[0] + w[1]) + (w[2] + w[3])) * INV_NUM_GRAPHS;
}

extern "C" void kernel_launch(void* const* d_in, const int* in_sizes, int n_in,
                              void* d_out, int out_size, void* d_ws, size_t ws_size,
                              hipStream_t stream) {
    const float* node_pos = (const float*)d_in[0];   // [N_NODES, 2] f32
    const int*   edge_idx = (const int*)d_in[1];     // [2, E] int32 (JAX x64 off)
    // d_in[2] = batch_idx — unused (mathematically irrelevant, see header)

    const int E = in_sizes[1] / 2;                   // 8388608
    const int* src = edge_idx;
    const int* dst = edge_idx + E;

    float* partials = (float*)d_ws;                  // 2048 floats = 8 KB scratch
    float* out = (float*)d_out;

    occlusion_partial<<<GRID1, BLOCK1, 0, stream>>>(
        reinterpret_cast<const float2*>(node_pos),
        reinterpret_cast<const v4i*>(src),
        reinterpret_cast<const v4i*>(dst),
        partials);
    occlusion_final<<<1, 256, 0, stream>>>(partials, out);
}

// Round 4
// 166.476 us; speedup vs baseline: 1.0022x; 1.0022x over previous
//
#include <hip/hip_runtime.h>
#include <hip/hip_fp16.h>

// Occlusion: out = (1/NUM_GRAPHS) * sum_e exp(-||pos[dst_e] - pos[src_e]||)
// batch_idx irrelevant (all segment ids in range; mean over segments ==
// total_sum / NUM_GRAPHS).
//
// The kernel is bound by random-gather REQUEST throughput (~0.34 line-req/
// cyc/CU measured, R1==R3 despite 4x MLP difference). Attack: cache the
// first 32768 nodes as fp16 half2 in 128 KB LDS (25% of uniform-random
// gathers become ds_reads under divergent exec masks -> 25% fewer L2
// requests). fp16 error bound ~1.4e-3 per edge, worst-case coherent
// output error ~11 << 39.68 threshold.

#define N_EDGES_C   8388608
#define STAGED      32768                    // nodes in LDS (128 KB of half2)
#define BLOCK1      1024                     // 16 waves; 1 block/CU (LDS-capped)
#define GRID1       256                      // exact cover of 256 CUs
#define TOTAL_THR   (GRID1 * BLOCK1)         // 262144
#define N_GROUPS    (N_EDGES_C / 4)          // 2097152 int4 groups
#define GPT         (N_GROUPS / TOTAL_THR)   // exactly 8 groups/thread
#define INV_NUM_GRAPHS (1.0f / 1024.0f)

typedef int v4i __attribute__((ext_vector_type(4)));  // nt-load-compatible

__global__ __launch_bounds__(BLOCK1) void occlusion_partial(
    const float2* __restrict__ pos,      // [N_NODES]
    const v4i*    __restrict__ src4,     // [E/4]
    const v4i*    __restrict__ dst4,     // [E/4]
    float*        __restrict__ partials) // [GRID1]
{
    __shared__ __half2 tab[STAGED];          // 128 KB (static size proven on gfx950)

    // --- stage nodes [0, STAGED) as fp16 pairs; coalesced float4 = 2 nodes/load ---
    {
        const float4* p4 = reinterpret_cast<const float4*>(pos);
        #pragma unroll
        for (int i = threadIdx.x; i < STAGED / 2; i += BLOCK1) {
            float4 v = p4[i];
            tab[2 * i + 0] = __floats2half2_rn(v.x, v.y);
            tab[2 * i + 1] = __floats2half2_rn(v.z, v.w);
        }
    }
    __syncthreads();

    const int tid = blockIdx.x * BLOCK1 + threadIdx.x;

    float acc0 = 0.f, acc1 = 0.f, acc2 = 0.f, acc3 = 0.f;
    #pragma unroll
    for (int j = 0; j < GPT; ++j) {
        const int g = tid + j * TOTAL_THR;
        const v4i s = __builtin_nontemporal_load(&src4[g]);
        const v4i d = __builtin_nontemporal_load(&dst4[g]);

        float2 ps[4], pd[4];
        #pragma unroll
        for (int k = 0; k < 4; ++k) {
            const int is = s[k];
            const int id = d[k];
            // divergent if/else is REQUIRED: exec-masked global_load only
            // generates L2 requests for active (non-staged) lanes.
            if (is < STAGED) {
                __half2 h = tab[is];
                ps[k] = make_float2(__low2float(h), __high2float(h));
            } else {
                ps[k] = pos[is];
            }
            if (id < STAGED) {
                __half2 h = tab[id];
                pd[k] = make_float2(__low2float(h), __high2float(h));
            } else {
                pd[k] = pos[id];
            }
        }

        float dx, dy;
        dx = pd[0].x - ps[0].x;  dy = pd[0].y - ps[0].y;
        acc0 += __expf(-sqrtf(dx * dx + dy * dy));
        dx = pd[1].x - ps[1].x;  dy = pd[1].y - ps[1].y;
        acc1 += __expf(-sqrtf(dx * dx + dy * dy));
        dx = pd[2].x - ps[2].x;  dy = pd[2].y - ps[2].y;
        acc2 += __expf(-sqrtf(dx * dx + dy * dy));
        dx = pd[3].x - ps[3].x;  dy = pd[3].y - ps[3].y;
        acc3 += __expf(-sqrtf(dx * dx + dy * dy));
    }
    float acc = (acc0 + acc1) + (acc2 + acc3);

    // --- wave-64 butterfly reduce ---
    #pragma unroll
    for (int off = 32; off > 0; off >>= 1)
        acc += __shfl_down(acc, off, 64);

    // cross-wave reduce: reuse tab as scratch (after barrier)
    __syncthreads();
    float* ws = reinterpret_cast<float*>(tab);
    const int lane = threadIdx.x & 63;
    const int wid  = threadIdx.x >> 6;              // 16 waves
    if (lane == 0) ws[wid] = acc;
    __syncthreads();

    if (threadIdx.x == 0) {
        float s = 0.f;
        #pragma unroll
        for (int w = 0; w < BLOCK1 / 64; ++w) s += ws[w];
        partials[blockIdx.x] = s;
    }
}

__global__ __launch_bounds__(256) void occlusion_final(
    const float* __restrict__ partials,  // [GRID1]
    float*       __restrict__ out)       // [1]
{
    float a = partials[threadIdx.x];     // GRID1 == 256

    #pragma unroll
    for (int off = 32; off > 0; off >>= 1)
        a += __shfl_down(a, off, 64);

    __shared__ float w[4];
    if ((threadIdx.x & 63) == 0) w[threadIdx.x >> 6] = a;
    __syncthreads();
    if (threadIdx.x == 0)
        out[0] = ((w[0] + w[1]) + (w[2] + w[3])) * INV_NUM_GRAPHS;
}

extern "C" void kernel_launch(void* const* d_in, const int* in_sizes, int n_in,
                              void* d_out, int out_size, void* d_ws, size_t ws_size,
                              hipStream_t stream) {
    const float* node_pos = (const float*)d_in[0];   // [N_NODES, 2] f32
    const int*   edge_idx = (const int*)d_in[1];     // [2, E] int32 (JAX x64 off)
    // d_in[2] = batch_idx — unused (mathematically irrelevant, see header)

    const int E = in_sizes[1] / 2;                   // 8388608
    const int* src = edge_idx;
    const int* dst = edge_idx + E;

    float* partials = (float*)d_ws;                  // 256 floats = 1 KB scratch
    float* out = (float*)d_out;

    occlusion_partial<<<GRID1, BLOCK1, 0, stream>>>(
        reinterpret_cast<const float2*>(node_pos),
        reinterpret_cast<const v4i*>(src),
        reinterpret_cast<const v4i*>(dst),
        partials);
    occlusion_final<<<1, 256, 0, stream>>>(partials, out);
}